// Round 4
// baseline (129.551 us; speedup 1.0000x reference)
//
#include <hip/hip_runtime.h>

// QuantizedConv2d int8 3x3, N=64, Cin=Cout=128, 56x56, pad=1 (value = input zp),
// int32 accum, per-channel requant. Harness widens integer arrays to int32
// (inputs AND output).
//
// R4: implicit GEMM, v_mfma_i32_32x32x32_i8, SWAPPED operands (A=weights,
// B=pixels) so D = [cout][px] and stores are lane-coalesced in px.
//  Block = (n, 2 output rows) = 112 px, all 128 cout. 256 thr = 4 waves.
//  Wave = 1 M-tile (32 px) x 4 N-tiles (32 cout); acc = 4 x 16 i32 (64 regs).
//  x staged to LDS [q=pixel][ci] bytes via dwordx4 loads + byte pack,
//  dword-XOR swizzle (q&7)<<2. Weights pre-packed, read from L2 per K-step.

#define CIN  128
#define COUT 128
#define HW   56
#define NPIX (HW * HW)
#define ROWS  2
#define QROWS 4
#define QCOLS 58
#define NQ (QROWS * QCOLS)   // 232

typedef int v4i  __attribute__((ext_vector_type(4)));
typedef int v16i __attribute__((ext_vector_type(16)));

// ---- pack weights: wp2 dword i = (step*128 + cout)*8 + dw ; step = t*4+cb ;
// byte b of dword dw -> ci = cb*32 + dw*4 + b, tap t.
__global__ __launch_bounds__(256) void pack_w2(const int* __restrict__ w_g,
                                               unsigned* __restrict__ wp2) {
    int i = blockIdx.x * 256 + threadIdx.x;
    if (i >= 36 * 128 * 8) return;
    int dw   = i & 7;
    int cout = (i >> 3) & 127;
    int step = i >> 10;          // 0..35
    int t  = step >> 2;
    int cb = step & 3;
    unsigned d = 0;
#pragma unroll
    for (int b = 0; b < 4; ++b) {
        int ci = cb * 32 + dw * 4 + b;
        int v = w_g[(cout * CIN + ci) * 9 + t];
        d |= (unsigned)(v & 0xFF) << (8 * b);
    }
    wp2[i] = d;
}

__global__ __launch_bounds__(256, 3) void conv_mfma(
    const int* __restrict__ x_g, const unsigned char* __restrict__ wp2,
    const int* __restrict__ bias, const float* __restrict__ in_s,
    const float* __restrict__ w_s, const float* __restrict__ out_s,
    const int* __restrict__ zp_in_p, const int* __restrict__ zp_out_p,
    int* __restrict__ out) {
    __shared__ unsigned xs[NQ * 32];   // 29696 B
    __shared__ float scs[COUT];
    __shared__ int   bis[COUT];

    const int n   = blockIdx.x / 28;
    const int ho0 = (blockIdx.x % 28) * ROWS;
    const int tid  = threadIdx.x;
    const int lane = tid & 63;
    const int wave = tid >> 6;

    const unsigned zpd = (unsigned)((*zp_in_p) & 0xFF) * 0x01010101u;

    // ---- requant constants to LDS ----
    if (tid < COUT) {
        scs[tid] = ((*in_s) / (*out_s)) * w_s[tid];
        bis[tid] = bias[tid];
    }

    // ---- halo column fill (q cols 0 and 57 are always padding) ----
    {
        int ci4 = tid >> 3;
        int r   = (tid >> 1) & 3;
        int q   = r * QCOLS + ((tid & 1) ? 57 : 0);
        xs[q * 32 + (ci4 ^ ((q & 7) << 2))] = zpd;
    }
    // ---- halo row fill (only edge blocks) ----
    if (ho0 == 0 || ho0 == HW - ROWS) {
        int rpad = (ho0 == 0) ? 0 : QROWS - 1;
#pragma unroll
        for (int it = 0; it < 7; ++it) {
            int idx = it * 256 + tid;        // 0..1791 = 56 cols x 32 ci4
            int c   = idx % HW + 1;
            int ci4 = idx / HW;
            int q   = rpad * QCOLS + c;
            xs[q * 32 + (ci4 ^ ((q & 7) << 2))] = zpd;
        }
    }
    // ---- interior x loads: dwordx4 (4 pixels x 1 ci), pack 4 -> 4 dwords ----
#pragma unroll
    for (int it = 0; it < 7; ++it) {
        int tau = it * 256 + tid;            // 0..1791 = 4r x 14cg x 32ci4
        int cg   = tau % 14;
        int rest = tau / 14;                 // 0..127
        int ci4  = rest & 31;
        int r    = rest >> 5;                // 0..3
        int h = ho0 + r - 1;
        if (h >= 0 && h < HW) {
            const int* xb = x_g + ((n * CIN + ci4 * 4) * HW + h) * HW + cg * 4;
            v4i L0 = *(const v4i*)xb;
            v4i L1 = *(const v4i*)(xb + NPIX);
            v4i L2 = *(const v4i*)(xb + 2 * NPIX);
            v4i L3 = *(const v4i*)(xb + 3 * NPIX);
#pragma unroll
            for (int j = 0; j < 4; ++j) {
                unsigned d = (unsigned)(L0[j] & 0xFF) |
                             ((unsigned)(L1[j] & 0xFF) << 8) |
                             ((unsigned)(L2[j] & 0xFF) << 16) |
                             ((unsigned)(L3[j] & 0xFF) << 24);
                int q = r * QCOLS + cg * 4 + 1 + j;
                xs[q * 32 + (ci4 ^ ((q & 7) << 2))] = d;
            }
        }
    }
    __syncthreads();

    // ---- compute: wave = M-tile, px = wave*32 + lane&31 (valid < 112) ----
    const int px  = wave * 32 + (lane & 31);
    const int pxc = px < ROWS * HW ? px : ROWS * HW - 1;
    const int qpx = (pxc / HW) * QCOLS + (pxc % HW);
    const int h4  = (lane >> 5) * 4;   // dword offset of K-half
    const unsigned char* bbase = wp2 + (lane & 31) * 32 + h4 * 4;

    v16i acc[4];
#pragma unroll
    for (int j = 0; j < 4; ++j) acc[j] = (v16i)0;

#pragma unroll 1
    for (int t = 0; t < 9; ++t) {
        const int q = qpx + (t / 3) * QCOLS + (t % 3);
        const int s = (q & 7) << 2;
        const unsigned char* bt = bbase + t * 4 * 4096;
#pragma unroll
        for (int cb = 0; cb < 4; ++cb) {
            v4i a = *(const v4i*)&xs[q * 32 + ((cb * 8 + h4) ^ s)];
            const unsigned char* bp = bt + cb * 4096;
            v4i b0 = *(const v4i*)(bp);
            v4i b1 = *(const v4i*)(bp + 1024);
            v4i b2 = *(const v4i*)(bp + 2048);
            v4i b3 = *(const v4i*)(bp + 3072);
            acc[0] = __builtin_amdgcn_mfma_i32_32x32x32_i8(b0, a, acc[0], 0, 0, 0);
            acc[1] = __builtin_amdgcn_mfma_i32_32x32x32_i8(b1, a, acc[1], 0, 0, 0);
            acc[2] = __builtin_amdgcn_mfma_i32_32x32x32_i8(b2, a, acc[2], 0, 0, 0);
            acc[3] = __builtin_amdgcn_mfma_i32_32x32x32_i8(b3, a, acc[3], 0, 0, 0);
        }
    }

    // ---- epilogue: D row = cout = (reg&3)+8*(reg>>2)+h4, col = px (lane) ----
    const float zpo = (float)(*zp_out_p);
    if (px < ROWS * HW) {
        int* ob = out + n * COUT * NPIX + ho0 * HW + px;  // + co*NPIX
#pragma unroll
        for (int nt = 0; nt < 4; ++nt) {
#pragma unroll
            for (int reg = 0; reg < 16; ++reg) {
                int co = nt * 32 + (reg & 3) + 8 * (reg >> 2) + h4;
                float f = fmaf((float)(acc[nt][reg] + bis[co]), scs[co], zpo);
                f = rintf(f);
                f = fminf(fmaxf(f, -128.0f), 127.0f);
                ob[co * NPIX] = (int)f;
            }
        }
    }
}

extern "C" void kernel_launch(void* const* d_in, const int* in_sizes, int n_in,
                              void* d_out, int out_size, void* d_ws, size_t ws_size,
                              hipStream_t stream) {
    const int* x_g      = (const int*)d_in[0];
    const int* w_g      = (const int*)d_in[1];
    const int* bias     = (const int*)d_in[2];
    const float* in_s   = (const float*)d_in[3];
    const float* w_s    = (const float*)d_in[4];
    const float* out_s  = (const float*)d_in[5];
    const int* zp_in_p  = (const int*)d_in[6];
    const int* zp_out_p = (const int*)d_in[7];
    int* outp = (int*)d_out;
    unsigned* wp2 = (unsigned*)d_ws;   // 147456 B

    pack_w2<<<(36 * 128 * 8 + 255) / 256, 256, 0, stream>>>(w_g, wp2);

    const int nblocks = 64 * (HW / ROWS);   // 1792
    conv_mfma<<<nblocks, 256, 0, stream>>>(x_g, (const unsigned char*)wp2, bias,
                                           in_s, w_s, out_s, zp_in_p, zp_out_p, outp);
}

// Round 5
// 76.478 us; speedup vs baseline: 1.6940x; 1.6940x over previous
//
#include <hip/hip_runtime.h>

// QuantizedConv2d int8 3x3, N=64, Cin=Cout=128, 56x56, pad=1 (value = input zp),
// int32 accum, per-channel requant. Harness widens integer arrays to int32
// (inputs AND output buffer).
//
// R5: implicit GEMM, v_mfma_i32_32x32x32_i8, swapped operands (D=[cout][px],
// coalesced stores). Block = (n, 4 rows) = 224 px, 4 waves; wave = 2 px-tiles
// x 4 cout-tiles (acc 2x4x16). Weights staged per K-halfstep (8KB) into LDS
// double-buffer via T14 async split (global->reg early, ds_write late), shared
// by all waves. B LDS layout XOR-swizzled at pack time -> conflict-free
// ds_read_b128. x staged once per block (dwordx4 + byte pack, q-XOR swizzle).

#define CIN  128
#define COUT 128
#define HW   56
#define NPIX (HW * HW)
#define ROWS  4
#define QROWS 6
#define QCOLS 58
#define NQ (QROWS * QCOLS)   // 348

typedef int v4i  __attribute__((ext_vector_type(4)));
typedef int v16i __attribute__((ext_vector_type(16)));

// ---- pack weights, swizzled ----
// step = t*4+cb (0..35); within step: 1024 dwords (128 cout x 8 dw).
// original in-chunk dword ic = cout*8 + dw ; granule g = ic>>2 = cout*2+(dw>>2)
// swizzled granule gs = g ^ ((g>>3)&7)  -> chunk dword = gs*4 + (dw&3).
// byte b of dword dw -> ci = cb*32 + dw*4 + b, tap t.
__global__ __launch_bounds__(256) void pack_w2(const int* __restrict__ w_g,
                                               unsigned* __restrict__ wp2) {
    int i = blockIdx.x * 256 + threadIdx.x;
    if (i >= 36 * 128 * 8) return;
    int dw   = i & 7;
    int cout = (i >> 3) & 127;
    int step = i >> 10;          // t*4 + cb
    int t  = step >> 2;
    int cb = step & 3;
    unsigned d = 0;
#pragma unroll
    for (int b = 0; b < 4; ++b) {
        int ci = cb * 32 + dw * 4 + b;
        int v = w_g[(cout * CIN + ci) * 9 + t];
        d |= (unsigned)(v & 0xFF) << (8 * b);
    }
    int g  = (cout << 1) | (dw >> 2);
    int gs = g ^ ((g >> 3) & 7);
    wp2[step * 1024 + gs * 4 + (dw & 3)] = d;
}

__global__ __launch_bounds__(256, 2) void conv_mfma(
    const int* __restrict__ x_g, const int* __restrict__ wp2,
    const int* __restrict__ bias, const float* __restrict__ in_s,
    const float* __restrict__ w_s, const float* __restrict__ out_s,
    const int* __restrict__ zp_in_p, const int* __restrict__ zp_out_p,
    int* __restrict__ out) {
    __shared__ unsigned xs[NQ * 32];        // 44544 B  [q][ci4^((q&7)<<2)]
    __shared__ char Bb[2][8192];            // 16384 B  K-halfstep double buffer
    __shared__ float scs[COUT];
    __shared__ int   bis[COUT];

    const int n   = blockIdx.x / 14;
    const int ho0 = (blockIdx.x % 14) * ROWS;
    const int tid    = threadIdx.x;
    const int lane   = tid & 63;
    const int wave   = tid >> 6;
    const int lane31 = lane & 31;
    const int hi     = lane >> 5;
    const int hi4    = hi * 4;

    const unsigned zpd = (unsigned)((*zp_in_p) & 0xFF) * 0x01010101u;

    // ---- requant constants ----
    if (tid < COUT) {
        scs[tid] = ((*in_s) / (*out_s)) * w_s[tid];
        bis[tid] = bias[tid];
    }

    // ---- halo column fill (q cols 0 and 57 always padding): 384 tasks ----
#pragma unroll
    for (int it = 0; it < 2; ++it) {
        int idx = it * 256 + tid;
        if (idx < QROWS * 2 * 32) {
            int ci4 = idx & 31;
            int r   = idx >> 6;                       // 0..5
            int q   = r * QCOLS + (((idx >> 5) & 1) ? QCOLS - 1 : 0);
            xs[q * 32 + (ci4 ^ ((q & 7) << 2))] = zpd;
        }
    }
    // ---- pad-row fill (edge blocks only): 56*32 tasks ----
    if (ho0 == 0 || ho0 == HW - ROWS) {
        int rpad = (ho0 == 0) ? 0 : QROWS - 1;
#pragma unroll
        for (int it = 0; it < 7; ++it) {
            int idx = it * 256 + tid;                 // < 1792
            int c   = idx % HW + 1;
            int ci4 = idx / HW;
            int q   = rpad * QCOLS + c;
            xs[q * 32 + (ci4 ^ ((q & 7) << 2))] = zpd;
        }
    }
    // ---- interior x: dwordx4 (4 px x 1 ci), pack -> 4 LDS dwords ----
#pragma unroll
    for (int it = 0; it < 11; ++it) {
        int tau = it * 256 + tid;                     // 6r x 14cg x 32ci4 = 2688
        if (tau < QROWS * 14 * 32) {
            int cg   = tau % 14;
            int rest = tau / 14;                      // 0..191
            int ci4  = rest & 31;
            int r    = rest >> 5;                     // 0..5
            int h = ho0 + r - 1;
            if ((unsigned)h < HW) {
                const int* xb = x_g + ((n * CIN + ci4 * 4) * HW + h) * HW + cg * 4;
                v4i L0 = *(const v4i*)xb;
                v4i L1 = *(const v4i*)(xb + NPIX);
                v4i L2 = *(const v4i*)(xb + 2 * NPIX);
                v4i L3 = *(const v4i*)(xb + 3 * NPIX);
#pragma unroll
                for (int j = 0; j < 4; ++j) {
                    unsigned d = (unsigned)(L0[j] & 0xFF) |
                                 ((unsigned)(L1[j] & 0xFF) << 8) |
                                 ((unsigned)(L2[j] & 0xFF) << 16) |
                                 ((unsigned)(L3[j] & 0xFF) << 24);
                    int q = r * QCOLS + cg * 4 + 1 + j;
                    xs[q * 32 + (ci4 ^ ((q & 7) << 2))] = d;
                }
            }
        }
    }
    // ---- stage B unit 0 (t=0, cb=0..1): 8KB, 32B/thread ----
    {
        const char* gsrc = (const char*)wp2 + tid * 16;
        v4i r0 = *(const v4i*)gsrc;
        v4i r1 = *(const v4i*)(gsrc + 4096);
        *(v4i*)(&Bb[0][tid * 16])        = r0;
        *(v4i*)(&Bb[0][4096 + tid * 16]) = r1;
    }
    __syncthreads();

    // ---- per-wave geometry ----
    int qb[2];
#pragma unroll
    for (int i = 0; i < 2; ++i) {
        int px = (wave * 2 + i) * 32 + lane31;
        if (px > ROWS * HW - 1) px = ROWS * HW - 1;   // wave3/i=1 clamp
        qb[i] = (px / HW) * QCOLS + (px % HW);
    }
    // B read offsets (swizzled), loop-invariant per nt
    int boff[4];
#pragma unroll
    for (int nt = 0; nt < 4; ++nt) {
        int g = nt * 64 + lane31 * 2 + hi;
        boff[nt] = (g ^ ((g >> 3) & 7)) * 16;
    }

    v16i acc[2][4];
#pragma unroll
    for (int i = 0; i < 2; ++i)
#pragma unroll
        for (int j = 0; j < 4; ++j) acc[i][j] = (v16i)0;

    // ---- K loop: 18 units (t 0..8 x half 0..1), unit = 2 cb slices (8KB) ----
#pragma unroll 1
    for (int u = 0; u < 18; ++u) {
        v4i r0, r1;
        if (u < 17) {   // T14: issue next-unit loads BEFORE compute
            const char* gsrc = (const char*)wp2 + (u + 1) * 8192 + tid * 16;
            r0 = *(const v4i*)gsrc;
            r1 = *(const v4i*)(gsrc + 4096);
        }
        const int t  = u >> 1;
        const int dq = (t / 3) * QCOLS + (t % 3);
        const int q0 = qb[0] + dq, q1 = qb[1] + dq;
        const int s0 = (q0 & 7) << 2, s1 = (q1 & 7) << 2;
        const char* bb = Bb[u & 1];
#pragma unroll
        for (int c = 0; c < 2; ++c) {
            const int cb = (u & 1) * 2 + c;
            v4i a0 = *(const v4i*)&xs[q0 * 32 + ((cb * 8 + hi4) ^ s0)];
            v4i a1 = *(const v4i*)&xs[q1 * 32 + ((cb * 8 + hi4) ^ s1)];
            const char* bc = bb + c * 4096;
            v4i b0 = *(const v4i*)(bc + boff[0]);
            v4i b1 = *(const v4i*)(bc + boff[1]);
            v4i b2 = *(const v4i*)(bc + boff[2]);
            v4i b3 = *(const v4i*)(bc + boff[3]);
            acc[0][0] = __builtin_amdgcn_mfma_i32_32x32x32_i8(b0, a0, acc[0][0], 0, 0, 0);
            acc[0][1] = __builtin_amdgcn_mfma_i32_32x32x32_i8(b1, a0, acc[0][1], 0, 0, 0);
            acc[0][2] = __builtin_amdgcn_mfma_i32_32x32x32_i8(b2, a0, acc[0][2], 0, 0, 0);
            acc[0][3] = __builtin_amdgcn_mfma_i32_32x32x32_i8(b3, a0, acc[0][3], 0, 0, 0);
            acc[1][0] = __builtin_amdgcn_mfma_i32_32x32x32_i8(b0, a1, acc[1][0], 0, 0, 0);
            acc[1][1] = __builtin_amdgcn_mfma_i32_32x32x32_i8(b1, a1, acc[1][1], 0, 0, 0);
            acc[1][2] = __builtin_amdgcn_mfma_i32_32x32x32_i8(b2, a1, acc[1][2], 0, 0, 0);
            acc[1][3] = __builtin_amdgcn_mfma_i32_32x32x32_i8(b3, a1, acc[1][3], 0, 0, 0);
        }
        if (u < 17) {   // T14: write-late into the other buffer, then barrier
            char* ld = &Bb[(u + 1) & 1][tid * 16];
            *(v4i*)ld          = r0;
            *(v4i*)(ld + 4096) = r1;
            __syncthreads();
        }
    }

    // ---- epilogue: D row = cout-in-tile = (reg&3)+8*(reg>>2)+hi4, col = px ----
    const float zpo = (float)(*zp_out_p);
#pragma unroll
    for (int i = 0; i < 2; ++i) {
        const int px = (wave * 2 + i) * 32 + lane31;
        if (px < ROWS * HW) {
            int* ob = out + n * COUT * NPIX + ho0 * HW + px;   // + co*NPIX
#pragma unroll
            for (int nt = 0; nt < 4; ++nt) {
#pragma unroll
                for (int reg = 0; reg < 16; ++reg) {
                    int co = nt * 32 + (reg & 3) + 8 * (reg >> 2) + hi4;
                    float f = fmaf((float)(acc[i][nt][reg] + bis[co]), scs[co], zpo);
                    f = rintf(f);
                    f = fminf(fmaxf(f, -128.0f), 127.0f);
                    ob[co * NPIX] = (int)f;
                }
            }
        }
    }
}

extern "C" void kernel_launch(void* const* d_in, const int* in_sizes, int n_in,
                              void* d_out, int out_size, void* d_ws, size_t ws_size,
                              hipStream_t stream) {
    const int* x_g      = (const int*)d_in[0];
    const int* w_g      = (const int*)d_in[1];
    const int* bias     = (const int*)d_in[2];
    const float* in_s   = (const float*)d_in[3];
    const float* w_s    = (const float*)d_in[4];
    const float* out_s  = (const float*)d_in[5];
    const int* zp_in_p  = (const int*)d_in[6];
    const int* zp_out_p = (const int*)d_in[7];
    int* outp = (int*)d_out;
    unsigned* wp2 = (unsigned*)d_ws;   // 147456 B

    pack_w2<<<(36 * 128 * 8 + 255) / 256, 256, 0, stream>>>(w_g, wp2);

    const int nblocks = 64 * (HW / ROWS);   // 896
    conv_mfma<<<nblocks, 256, 0, stream>>>(x_g, (const int*)wp2, bias,
                                           in_s, w_s, out_s, zp_in_p, zp_out_p, outp);
}